// Round 4
// baseline (131.170 us; speedup 1.0000x reference)
//
#include <hip/hip_runtime.h>

// Depthwise 41-tap separable gaussian blur of flow = noise*2-1.
// [16, 512, 512, 2] fp32, SAME zero padding.
//
// R8: full-width fused kernel (R7 structure) at 2x occupancy. R7 measured
// 52us with VALUBusy 18% / HBM 21% / Occupancy 38%: latency-bound at
// 4 waves/SIMD (70.8KB LDS -> 2 blocks/CU, grid exactly 2/CU, so barriers
// had no spare blocks to cover them). Measured VALU-busy time (18% x 52us
// = 9.4us) matches the 8.75us FMA floor, so compute is fine -- the stall
// is memory latency + barrier drain. Fix: FTY 16 -> 8 rows/block:
//   LDS 35.4KB -> 4 blocks/CU = 32 waves/CU (HW max), 8 waves/SIMD;
//   grid 1024 = exactly 4/CU, so 3 other blocks run while one barriers.
//   acc[8] = 16 VGPR, safe under the 64-VGPR cap of (512,8) (the R5 spill
//   was acc[16]=32 VGPR against the same cap).
// Vertical halo ratio worsens (48 rows loaded per 8 output rows) but the
// re-reads are L2-hits: XCD-chunk swizzle gives each XCD 128 consecutive
// blocks = 2 whole images (4.2MB ~ one 4MB XCD L2), all co-resident.
//   phase 1: vertical 41-tap conv, thread = one x column (dense float2
//            loads), 8 output rows in registers -> LDS (zero-padded rows).
//   phase 2: horizontal 41-tap conv from LDS, sliding window, 8 cols/thread
//            (uniform 4 lanes/bank-pair at 8B/lane = wave64 LDS floor).
//   phase 3: results -> aliased LDS region -> 8 dense full-row 4KB stores.
#define NB   16
#define H    512
#define W    512
#define KW   41
#define HALO 20

#define FTY   8                   // output rows per block
#define FROWS (FTY + KW - 1)      // 48 input rows loaded
#define SSTR  553                 // mid row stride (float2): 512 + 40 pad + 1
#define OSTR  513                 // out-stage row stride (float2)
#define HPX   8                   // horizontal outputs per thread

// Raw gaussian taps exp(-d^2/50), d=-20..20; (1/sum)^2 folded into INV_S2.
constexpr float G[KW] = {
  0.0003354626f, 0.0007318024f, 0.0015338104f, 0.0030887172f,
  0.0059760229f, 0.0111089965f, 0.0198410947f, 0.0340474548f,
  0.0561347628f, 0.0889216176f, 0.1353352832f, 0.1978986990f,
  0.2780373005f, 0.3753110988f, 0.4867522560f, 0.6065306597f,
  0.7261490371f, 0.8352702114f, 0.9231163464f, 0.9801986733f,
  1.0f,
  0.9801986733f, 0.9231163464f, 0.8352702114f, 0.7261490371f,
  0.6065306597f, 0.4867522560f, 0.3753110988f, 0.2780373005f,
  0.1978986990f, 0.1353352832f, 0.0889216176f, 0.0561347628f,
  0.0340474548f, 0.0198410947f, 0.0111089965f, 0.0059760229f,
  0.0030887172f, 0.0015338104f, 0.0007318024f, 0.0003354626f
};

constexpr float gsum() { float s = 0.f; for (int i = 0; i < KW; ++i) s += G[i]; return s; }
constexpr float INV_S2 = 1.0f / (gsum() * gsum());

__global__ __launch_bounds__(512, 8)   // 64-VGPR cap -> 8 waves/SIMD possible
void randflow_fused_kernel(const float* __restrict__ noise, float* __restrict__ out) {
    __shared__ float2 smem[FTY * SSTR];   // 4424 float2 = 35392 B -> 4 blocks/CU

    const int tid = threadIdx.x;          // 0..511 = x column

    // grid (64, 16) -> 1024 blocks; physical id dispatches to XCD id%8.
    // Bijective chunk swizzle: sid = (id&7)*128 + id/8 gives each XCD 128
    // consecutive (y-tile, batch) slots = 2 whole images, all co-resident
    // (4 blocks/CU x 32 CU/XCD) -> 40-row y-halo re-reads are local-L2 hits.
    int id = blockIdx.x + 64 * blockIdx.y;
    id = ((id & 7) << 7) | (id >> 3);
    const int ly = id & 63;               // 64 y-tiles of 8 rows
    const int lb = id >> 6;               // 16 batches
    const int y0 = ly * FTY;

    // zero the 20-col left/right borders of all 8 LDS rows (image zero-pad)
    if (tid < FTY * 2 * HALO) {                   // 320 < 512: one step
        const int row = tid / 40;                 // const divide -> magic mul
        const int c   = tid - row * 40;
        const int col = (c < HALO) ? c : (c + W); // [0,20) U [532,552)
        smem[row * SSTR + col] = make_float2(0.f, 0.f);
    }

    // ---- phase 1: vertical 41-tap conv on flow = noise*2-1.
    // Thread = column tid, both channels as float2; 48 dense 4KB wave-row
    // loads; zero-pad in y via select on clamped (always-legal) addresses.
    {
        const float* __restrict__ src = noise + ((size_t)lb * H * W + tid) * 2;
        float2 acc[FTY];
        #pragma unroll
        for (int p = 0; p < FTY; ++p) acc[p] = make_float2(0.f, 0.f);

        const int ysb = y0 - HALO;
        #pragma unroll
        for (int j = 0; j < FROWS; ++j) {         // 48 rows
            const int ys = ysb + j;
            const int cy = min(max(ys, 0), H - 1);
            const float a  = (ys == cy) ? 2.0f : 0.0f;   // y-validity select
            const float bb = (ys == cy) ? -1.0f : 0.0f;
            const float2 u = *(const float2*)(src + (size_t)cy * (W * 2));
            float2 v;
            v.x = __builtin_fmaf(u.x, a, bb);
            v.y = __builtin_fmaf(u.y, a, bb);
            #pragma unroll
            for (int p = 0; p < FTY; ++p) {
                const int t = j - p;              // compile-time after unroll
                if (t >= 0 && t < KW) {
                    acc[p].x = __builtin_fmaf(G[t], v.x, acc[p].x);
                    acc[p].y = __builtin_fmaf(G[t], v.y, acc[p].y);
                }
            }
        }
        #pragma unroll
        for (int p = 0; p < FTY; ++p)             // lanes dense along x
            smem[p * SSTR + HALO + tid] = acc[p];
    }
    __syncthreads();

    // ---- phase 2: horizontal 41-tap conv in LDS, sliding window.
    // Thread = (row y, 8-col group xg); 48 reads per 8 outputs.
    // Banks: (18y + 16(xg&1) + 2j) mod 32 -> 16 distinct even residues,
    // uniform 4 lanes/bank-pair = the wave64 8-byte floor (conflict-free).
    const int y  = tid & 7;
    const int xg = tid >> 3;                      // 0..63
    const int x0 = xg * HPX;
    float2 facc[HPX];
    {
        #pragma unroll
        for (int p = 0; p < HPX; ++p) facc[p] = make_float2(0.f, 0.f);
        #pragma unroll
        for (int j = 0; j < HPX + KW - 1; ++j) {  // 48 padded cols x0..x0+47
            const float2 v = smem[y * SSTR + x0 + j];
            #pragma unroll
            for (int p = 0; p < HPX; ++p) {
                const int t = j - p;
                if (t >= 0 && t < KW) {
                    facc[p].x = __builtin_fmaf(G[t], v.x, facc[p].x);
                    facc[p].y = __builtin_fmaf(G[t], v.y, facc[p].y);
                }
            }
        }
    }
    __syncthreads();   // all phase-2 reads done; safe to overwrite alias

    // out-stage (aliases smem): scaled results, transpose-friendly layout
    #pragma unroll
    for (int p = 0; p < HPX; ++p) {
        float2 r;
        r.x = facc[p].x * INV_S2;
        r.y = facc[p].y * INV_S2;
        smem[y * OSTR + x0 + p] = r;
    }
    __syncthreads();

    // ---- phase 3: 8 dense full-row 4KB stores, lanes dense along x.
    float* __restrict__ ob = out + (((size_t)lb * H + y0) * W) * 2;
    #pragma unroll
    for (int k = 0; k < FTY; ++k)
        *(float2*)(ob + (size_t)k * (W * 2) + tid * 2) = smem[k * OSTR + tid];
}

extern "C" void kernel_launch(void* const* d_in, const int* in_sizes, int n_in,
                              void* d_out, int out_size, void* d_ws, size_t ws_size,
                              hipStream_t stream) {
    // d_in[0] = inputs [16,512,512,1]  -- UNUSED by the reference
    // d_in[1] = rand_noise [16,512,512,2] fp32
    const float* noise = (const float*)d_in[1];
    float* out = (float*)d_out;

    randflow_fused_kernel<<<dim3(H / FTY / 8 * 8, NB), dim3(512), 0, stream>>>(noise, out);
}

// Round 5
// 102.060 us; speedup vs baseline: 1.2852x; 1.2852x over previous
//
#include <hip/hip_runtime.h>

// Depthwise 41-tap separable gaussian blur of flow = noise*2-1.
// [16, 512, 512, 2] fp32, SAME zero padding.
//
// R9: R8 structure with the launch-bounds spill fixed. Confirmed twice now
// (R5: (256,8) -> VGPR_Count 32; R8: (512,8) -> VGPR_Count 32, WRITE_SIZE
// 96MB = output + 62MB scratch): on this toolchain min_waves=8 caps the
// allocator at 32 VGPRs (256/waves, not 512/waves) and force-spills the
// accumulators. Fix: keep __launch_bounds__(512, 4) (128-VGPR cap; R7
// compiled to exactly 64 VGPR with 2x this kernel's accumulator state).
// Runtime occupancy comes from ACTUAL usage, not the bound: <=64 VGPR
// allows 32 waves/CU (reg-file halves only above 64), and 35.4KB LDS
// allows 4 blocks/CU = 32 waves/CU. So we get R8's target occupancy
// (8 waves/SIMD, 4 blocks/CU round-robining across barriers) without the
// spill.
//   phase 1: vertical 41-tap conv, thread = one x column (dense float2
//            loads), 8 output rows in registers -> LDS (zero-padded rows).
//   phase 2: horizontal 41-tap conv from LDS, sliding window, 8 cols/thread
//            (uniform 4 lanes/bank-pair at 8B/lane = wave64 LDS floor).
//   phase 3: results -> aliased LDS region -> 8 dense full-row 4KB stores.
// XCD-chunk swizzle: each XCD owns 128 consecutive (y-tile,batch) slots =
// 2 whole images (~4.2MB ~ its 4MB L2), all co-resident -> the 40-row
// vertical halo re-reads (6x request amplification at FTY=8) are L2 hits.
#define NB   16
#define H    512
#define W    512
#define KW   41
#define HALO 20

#define FTY   8                   // output rows per block
#define FROWS (FTY + KW - 1)      // 48 input rows loaded
#define SSTR  553                 // mid row stride (float2): 512 + 40 pad + 1
#define OSTR  513                 // out-stage row stride (float2)
#define HPX   8                   // horizontal outputs per thread

// Raw gaussian taps exp(-d^2/50), d=-20..20; (1/sum)^2 folded into INV_S2.
constexpr float G[KW] = {
  0.0003354626f, 0.0007318024f, 0.0015338104f, 0.0030887172f,
  0.0059760229f, 0.0111089965f, 0.0198410947f, 0.0340474548f,
  0.0561347628f, 0.0889216176f, 0.1353352832f, 0.1978986990f,
  0.2780373005f, 0.3753110988f, 0.4867522560f, 0.6065306597f,
  0.7261490371f, 0.8352702114f, 0.9231163464f, 0.9801986733f,
  1.0f,
  0.9801986733f, 0.9231163464f, 0.8352702114f, 0.7261490371f,
  0.6065306597f, 0.4867522560f, 0.3753110988f, 0.2780373005f,
  0.1978986990f, 0.1353352832f, 0.0889216176f, 0.0561347628f,
  0.0340474548f, 0.0198410947f, 0.0111089965f, 0.0059760229f,
  0.0030887172f, 0.0015338104f, 0.0007318024f, 0.0003354626f
};

constexpr float gsum() { float s = 0.f; for (int i = 0; i < KW; ++i) s += G[i]; return s; }
constexpr float INV_S2 = 1.0f / (gsum() * gsum());

__global__ __launch_bounds__(512, 4)   // 128-VGPR cap; actual usage <=64 -> 8 waves/SIMD
void randflow_fused_kernel(const float* __restrict__ noise, float* __restrict__ out) {
    __shared__ float2 smem[FTY * SSTR];   // 4424 float2 = 35392 B -> 4 blocks/CU

    const int tid = threadIdx.x;          // 0..511 = x column

    // grid (64, 16) -> 1024 blocks; physical id dispatches to XCD id%8.
    // Bijective chunk swizzle: sid = (id&7)*128 + id/8 gives each XCD 128
    // consecutive (y-tile, batch) slots = 2 whole images, all co-resident
    // (4 blocks/CU x 32 CU/XCD) -> 40-row y-halo re-reads are local-L2 hits.
    int id = blockIdx.x + 64 * blockIdx.y;
    id = ((id & 7) << 7) | (id >> 3);
    const int ly = id & 63;               // 64 y-tiles of 8 rows
    const int lb = id >> 6;               // 16 batches
    const int y0 = ly * FTY;

    // zero the 20-col left/right borders of all 8 LDS rows (image zero-pad)
    if (tid < FTY * 2 * HALO) {                   // 320 < 512: one step
        const int row = tid / 40;                 // const divide -> magic mul
        const int c   = tid - row * 40;
        const int col = (c < HALO) ? c : (c + W); // [0,20) U [532,552)
        smem[row * SSTR + col] = make_float2(0.f, 0.f);
    }

    // ---- phase 1: vertical 41-tap conv on flow = noise*2-1.
    // Thread = column tid, both channels as float2; 48 dense 4KB wave-row
    // loads; zero-pad in y via select on clamped (always-legal) addresses.
    {
        const float* __restrict__ src = noise + ((size_t)lb * H * W + tid) * 2;
        float2 acc[FTY];
        #pragma unroll
        for (int p = 0; p < FTY; ++p) acc[p] = make_float2(0.f, 0.f);

        const int ysb = y0 - HALO;
        #pragma unroll
        for (int j = 0; j < FROWS; ++j) {         // 48 rows
            const int ys = ysb + j;
            const int cy = min(max(ys, 0), H - 1);
            const float a  = (ys == cy) ? 2.0f : 0.0f;   // y-validity select
            const float bb = (ys == cy) ? -1.0f : 0.0f;
            const float2 u = *(const float2*)(src + (size_t)cy * (W * 2));
            float2 v;
            v.x = __builtin_fmaf(u.x, a, bb);
            v.y = __builtin_fmaf(u.y, a, bb);
            #pragma unroll
            for (int p = 0; p < FTY; ++p) {
                const int t = j - p;              // compile-time after unroll
                if (t >= 0 && t < KW) {
                    acc[p].x = __builtin_fmaf(G[t], v.x, acc[p].x);
                    acc[p].y = __builtin_fmaf(G[t], v.y, acc[p].y);
                }
            }
        }
        #pragma unroll
        for (int p = 0; p < FTY; ++p)             // lanes dense along x
            smem[p * SSTR + HALO + tid] = acc[p];
    }
    __syncthreads();

    // ---- phase 2: horizontal 41-tap conv in LDS, sliding window.
    // Thread = (row y, 8-col group xg); 48 reads per 8 outputs.
    // Banks: (18y + 16(xg&1) + 2j) mod 32 -> 16 distinct even residues,
    // uniform 4 lanes/bank-pair = the wave64 8-byte floor (conflict-free).
    const int y  = tid & 7;
    const int xg = tid >> 3;                      // 0..63
    const int x0 = xg * HPX;
    float2 facc[HPX];
    {
        #pragma unroll
        for (int p = 0; p < HPX; ++p) facc[p] = make_float2(0.f, 0.f);
        #pragma unroll
        for (int j = 0; j < HPX + KW - 1; ++j) {  // 48 padded cols x0..x0+47
            const float2 v = smem[y * SSTR + x0 + j];
            #pragma unroll
            for (int p = 0; p < HPX; ++p) {
                const int t = j - p;
                if (t >= 0 && t < KW) {
                    facc[p].x = __builtin_fmaf(G[t], v.x, facc[p].x);
                    facc[p].y = __builtin_fmaf(G[t], v.y, facc[p].y);
                }
            }
        }
    }
    __syncthreads();   // all phase-2 reads done; safe to overwrite alias

    // out-stage (aliases smem): scaled results, transpose-friendly layout
    #pragma unroll
    for (int p = 0; p < HPX; ++p) {
        float2 r;
        r.x = facc[p].x * INV_S2;
        r.y = facc[p].y * INV_S2;
        smem[y * OSTR + x0 + p] = r;
    }
    __syncthreads();

    // ---- phase 3: 8 dense full-row 4KB stores, lanes dense along x.
    float* __restrict__ ob = out + (((size_t)lb * H + y0) * W) * 2;
    #pragma unroll
    for (int k = 0; k < FTY; ++k)
        *(float2*)(ob + (size_t)k * (W * 2) + tid * 2) = smem[k * OSTR + tid];
}

extern "C" void kernel_launch(void* const* d_in, const int* in_sizes, int n_in,
                              void* d_out, int out_size, void* d_ws, size_t ws_size,
                              hipStream_t stream) {
    // d_in[0] = inputs [16,512,512,1]  -- UNUSED by the reference
    // d_in[1] = rand_noise [16,512,512,2] fp32
    const float* noise = (const float*)d_in[1];
    float* out = (float*)d_out;

    randflow_fused_kernel<<<dim3(H / FTY, NB), dim3(512), 0, stream>>>(noise, out);
}